// Round 1
// 119.666 us; speedup vs baseline: 1.0280x; 1.0280x over previous
//
#include <hip/hip_runtime.h>
#include <stdint.h>

typedef __attribute__((ext_vector_type(8))) short short8;
typedef __attribute__((ext_vector_type(4))) float f32x4;

#define BB 8
#define CC 256
#define PP 1024
#define NH 4
#define DH 64

// q-scale: dh^-0.5 * log2(e), so softmax can use raw v_exp (exp2)
#define QSCALE 0.18033688f

__device__ __forceinline__ unsigned short f2bf(float f) {
  union { float f; unsigned u; } v; v.f = f;
  unsigned r = v.u + 0x7FFFu + ((v.u >> 16) & 1u);
  return (unsigned short)(r >> 16);
}

__device__ __forceinline__ f32x4 mfma16(short8 a, short8 b, f32x4 c) {
  return __builtin_amdgcn_mfma_f32_16x16x32_bf16(a, b, c, 0, 0, 0);
}

// -------- Kernel 1: GroupNorm partial sums (512 blk) + weight cvt (256 blk) -
__global__ __launch_bounds__(256) void prep(
    const float* __restrict__ x, float2* __restrict__ part,
    const float* __restrict__ qkvw, const float* __restrict__ projw,
    unsigned short* __restrict__ wall) {
  int blk = blockIdx.x;
  int tid = threadIdx.x;
  if (blk < 512) {
    int sl = blk & 7, g = (blk >> 3) & 7, b = blk >> 6;
    const float4* xb =
        (const float4*)(x + (size_t)(b * CC + g * 32) * PP) + sl * 1024;
    float s = 0.f, q = 0.f;
    for (int i = tid; i < 1024; i += 256) {
      float4 v = xb[i];
      s += v.x + v.y + v.z + v.w;
      q += v.x * v.x + v.y * v.y + v.z * v.z + v.w * v.w;
    }
    for (int off = 32; off > 0; off >>= 1) {
      s += __shfl_down(s, off);
      q += __shfl_down(q, off);
    }
    __shared__ float rs[4], rq[4];
    int w = tid >> 6;
    if ((tid & 63) == 0) { rs[w] = s; rq[w] = q; }
    __syncthreads();
    if (tid == 0)
      part[blk] = make_float2(rs[0] + rs[1] + rs[2] + rs[3],
                              rq[0] + rq[1] + rq[2] + rq[3]);
  } else {
    int i4 = (blk - 512) * 256 + tid;  // 65536 float4s total
    float4 v = (i4 < 49152) ? ((const float4*)qkvw)[i4]
                            : ((const float4*)projw)[i4 - 49152];
    ushort4 o;
    o.x = f2bf(v.x); o.y = f2bf(v.y); o.z = f2bf(v.z); o.w = f2bf(v.w);
    ((ushort4*)wall)[i4] = o;
  }
}

// ------------- Kernel 2: fused GroupNorm + QKV GEMM ------------------------
// Replaces norm_t + qkv_gemm: A-tile is built from raw fp32 x with in-flight
// normalize (stats finalized from `part` at block start) + bf16 convert +
// transpose into LDS. Eliminates the xnT round-trip (8 MB) and one launch.
// q,k: [b][h][p][64]; v stored TRANSPOSED: vT[b][h][ch][p]
__global__ __launch_bounds__(256) void nqkv(
    const float* __restrict__ x, const float2* __restrict__ part,
    const float* __restrict__ gamma, const float* __restrict__ beta,
    const unsigned short* __restrict__ wbf, const float* __restrict__ qkvb,
    unsigned short* __restrict__ qb, unsigned short* __restrict__ kb,
    unsigned short* __restrict__ vT) {
  int p0 = blockIdx.x * 128, o0 = blockIdx.y * 128, b = blockIdx.z;
  int tid = threadIdx.x;
  int w = tid >> 6, lane = tid & 63, lq = lane >> 4, ln = lane & 15;
  int wy = w >> 1, wx = w & 1;
  __shared__ unsigned short A_l[128][40];
  __shared__ unsigned short B_l[128][40];
  __shared__ float scs[256], shs[256];
  __shared__ float g_m[8], g_r[8];
  // finalize group stats (one group = 32 channels = one K-slice)
  if (tid < 8) {
    float S = 0.f, Q = 0.f;
    for (int i = 0; i < 8; ++i) {
      float2 pp = part[b * 64 + tid * 8 + i];
      S += pp.x; Q += pp.y;
    }
    float mean = S * (1.f / 32768.f);
    float var = Q * (1.f / 32768.f) - mean * mean;
    g_m[tid] = mean;
    g_r[tid] = rsqrtf(var + 1e-5f);
  }
  __syncthreads();
  {
    int c = tid;
    float sc = g_r[c >> 5] * gamma[c];
    scs[c] = sc;
    shs[c] = beta[c] - g_m[c >> 5] * sc;
  }
  __syncthreads();
  f32x4 acc[4][4];
  for (int i = 0; i < 4; ++i)
    for (int j = 0; j < 4; ++j) acc[i][j] = (f32x4){0.f, 0.f, 0.f, 0.f};
  int cc = tid >> 3, ps = tid & 7;  // A-stage mapping: 32 c-rows x 8 p-segs
  for (int kc = 0; kc < 256; kc += 32) {
    // ---- A stage: read fp32 x row (c = kc+cc), normalize, bf16, transpose
    {
      float sc = scs[kc + cc], sh = shs[kc + cc];
      const float* xr = x + ((size_t)(b * CC + kc + cc)) * PP + p0;
#pragma unroll
      for (int i = 0; i < 4; ++i) {
        int p = ps * 4 + 32 * i;
        float4 v = *(const float4*)(xr + p);
        A_l[p + 0][cc] = f2bf(v.x * sc + sh);
        A_l[p + 1][cc] = f2bf(v.y * sc + sh);
        A_l[p + 2][cc] = f2bf(v.z * sc + sh);
        A_l[p + 3][cc] = f2bf(v.w * sc + sh);
      }
    }
    // ---- B stage: bf16 weights, vectorized
    for (int it = 0; it < 2; ++it) {
      int l = tid + 256 * it;
      int row = l >> 2, seg = l & 3;
      *(short8*)&B_l[row][seg * 8] =
          *(const short8*)(wbf + (size_t)(o0 + row) * CC + kc + seg * 8);
    }
    __syncthreads();
    short8 af[4], bfr[4];
    for (int i = 0; i < 4; ++i)
      af[i] = *(const short8*)&A_l[wy * 64 + i * 16 + ln][lq * 8];
    for (int j = 0; j < 4; ++j)
      bfr[j] = *(const short8*)&B_l[wx * 64 + j * 16 + ln][lq * 8];
    for (int i = 0; i < 4; ++i)
      for (int j = 0; j < 4; ++j) acc[i][j] = mfma16(af[i], bfr[j], acc[i][j]);
    __syncthreads();
  }
  for (int i = 0; i < 4; ++i) {
    for (int j = 0; j < 4; ++j) {
      int o = o0 + wx * 64 + j * 16 + ln;
      int s = o >> 8, h = (o >> 6) & 3, ch = o & 63;
      float bias = qkvb[o];
      float mul = (s == 0) ? QSCALE : 1.0f;  // fold dh^-0.5 * log2e into q
      size_t bh = (size_t)b * NH + h;
      int pbase = p0 + wy * 64 + i * 16 + lq * 4;
      if (s == 2) {
        // pack 4 consecutive-p values -> one 8B store (was 4x 2B scatter)
        union { unsigned short u[4]; unsigned long long ll; } pk;
#pragma unroll
        for (int r = 0; r < 4; ++r) pk.u[r] = f2bf(acc[i][j][r] + bias);
        *(unsigned long long*)(vT + (bh * DH + ch) * PP + pbase) = pk.ll;
      } else {
        unsigned short* dst = (s == 0) ? qb : kb;
#pragma unroll
        for (int r = 0; r < 4; ++r)
          dst[(bh * PP + pbase + r) * DH + ch] =
              f2bf((acc[i][j][r] + bias) * mul);
      }
    }
  }
}

// ------------- Kernel 3: flash attention, S^T form -------------------------
// QK computed as S^T = K Q^T (swap mfma operands): C/D col = d, rows = e.
// -> P-regs contiguous in e => 8x ds_write_b64 (vs 32x b16); row-sum is
// per-lane scalar (d = ln), reduced once at end via shfl_xor(16/32).
// PV as O = V^T(.)P: A = V_l rows ch, B = P_l rows d (b128 reads unchanged).
// q pre-scaled by dh^-0.5*log2e -> softmax = exp2 (raw v_exp_f32).
// No-max softmax safe: s = log2e*0.125*q.k ~ N(0,1.44); clamp 86 blocks ovf.
__global__ __launch_bounds__(256) void attn(
    const unsigned short* __restrict__ qb, const unsigned short* __restrict__ kb,
    const unsigned short* __restrict__ vT, unsigned short* __restrict__ attnT) {
  int d0 = blockIdx.x * 64, h = blockIdx.y, b = blockIdx.z;
  int tid = threadIdx.x;
  int w = tid >> 6, lane = tid & 63, lq = lane >> 4, ln = lane & 15;
  size_t bh = (size_t)b * NH + h;
  const unsigned short* qbase = qb + bh * PP * DH;
  const unsigned short* kbase = kb + bh * PP * DH;
  const unsigned short* vbase = vT + bh * DH * PP;
  __shared__ unsigned short K_l[128][72];   // [e][ch]
  __shared__ unsigned short V_l[64][136];   // [ch][e]
  __shared__ unsigned short P_l[64][140];   // [d][e], b64-aligned rows
  unsigned short (*O_l)[72] = (unsigned short (*)[72]) & P_l[0][0];

  int ke = tid >> 1, kseg = tid & 1;   // K: 128 rows x 2 half-rows x 32 shorts
  int vch = tid >> 2, vseg = tid & 3;  // V: 64 rows x 4 quarter-rows x 32 shorts

  short8 qf[2];
  {
    int d = d0 + w * 16 + ln;
    qf[0] = *(const short8*)(qbase + (size_t)d * DH + lq * 8);
    qf[1] = *(const short8*)(qbase + (size_t)d * DH + 32 + lq * 8);
  }
  float l_sum = 0.f;  // partial row-sum for d = w*16+ln (this lane's column)
  f32x4 o_acc[4];
  for (int i = 0; i < 4; ++i) o_acc[i] = (f32x4){0.f, 0.f, 0.f, 0.f};

  // register prefetch buffers: 4x short8 each = full 32-short span per thread
  short8 kr[4], vr[4];
#pragma unroll
  for (int i = 0; i < 4; ++i)
    kr[i] = *(const short8*)(kbase + (size_t)ke * DH + kseg * 32 + i * 8);
#pragma unroll
  for (int i = 0; i < 4; ++i)
    vr[i] = *(const short8*)(vbase + (size_t)vch * PP + vseg * 32 + i * 8);

  for (int e0 = 0; e0 < PP; e0 += 128) {
#pragma unroll
    for (int i = 0; i < 4; ++i)
      *(short8*)&K_l[ke][kseg * 32 + i * 8] = kr[i];
#pragma unroll
    for (int i = 0; i < 4; ++i)
      *(short8*)&V_l[vch][vseg * 32 + i * 8] = vr[i];
    if (e0 + 128 < PP) {
      int en = e0 + 128;
#pragma unroll
      for (int i = 0; i < 4; ++i)
        kr[i] = *(const short8*)(kbase + (size_t)(en + ke) * DH + kseg * 32 + i * 8);
#pragma unroll
      for (int i = 0; i < 4; ++i)
        vr[i] = *(const short8*)(vbase + (size_t)vch * PP + en + vseg * 32 + i * 8);
    }
    __syncthreads();
    // S^T = K Q^T : 8 subtiles of 16 e. A = K_l rows e, B = Q rows d.
    // C/D: col = d = w*16+ln, row = e = ns*16 + lq*4 + r.
    f32x4 sc[8];
#pragma unroll
    for (int ns = 0; ns < 8; ++ns) {
      f32x4 a = (f32x4){0.f, 0.f, 0.f, 0.f};
      a = mfma16(*(const short8*)&K_l[ns * 16 + ln][lq * 8], qf[0], a);
      a = mfma16(*(const short8*)&K_l[ns * 16 + ln][32 + lq * 8], qf[1], a);
      sc[ns] = a;
    }
    // exp2 + pack 4 contiguous-e values -> one b64 LDS write per subtile
#pragma unroll
    for (int ns = 0; ns < 8; ++ns) {
      float p0 = __builtin_amdgcn_exp2f(fminf(sc[ns][0], 86.f));
      float p1 = __builtin_amdgcn_exp2f(fminf(sc[ns][1], 86.f));
      float p2 = __builtin_amdgcn_exp2f(fminf(sc[ns][2], 86.f));
      float p3 = __builtin_amdgcn_exp2f(fminf(sc[ns][3], 86.f));
      l_sum += (p0 + p1) + (p2 + p3);
      union { unsigned short u[4]; unsigned long long ll; } pk;
      pk.u[0] = f2bf(p0); pk.u[1] = f2bf(p1);
      pk.u[2] = f2bf(p2); pk.u[3] = f2bf(p3);
      *(unsigned long long*)&P_l[w * 16 + ln][ns * 16 + lq * 4] = pk.ll;
    }
    // PV: C[ch][d] += sum_e V_l[ch][e] * P_l[d][e]; 4 k-chunks of 32 e
#pragma unroll
    for (int t = 0; t < 4; ++t) {
      short8 pb = *(const short8*)&P_l[w * 16 + ln][t * 32 + lq * 8];
#pragma unroll
      for (int cs = 0; cs < 4; ++cs)
        o_acc[cs] = mfma16(
            *(const short8*)&V_l[cs * 16 + ln][t * 32 + lq * 8], pb, o_acc[cs]);
    }
    __syncthreads();
  }
  // cross-quad row-sum reduce (d = w*16+ln lives in lane ln of every quad)
  float rsum = l_sum;
  rsum += __shfl_xor(rsum, 16);
  rsum += __shfl_xor(rsum, 32);
  float inv = 1.f / rsum;
  // O frag: lane holds col d = w*16+ln, rows ch = cs*16+lq*4+r -> b64 packs
#pragma unroll
  for (int cs = 0; cs < 4; ++cs) {
    union { unsigned short u[4]; unsigned long long ll; } pk;
#pragma unroll
    for (int r = 0; r < 4; ++r) pk.u[r] = f2bf(o_acc[cs][r] * inv);
    *(unsigned long long*)&O_l[w * 16 + ln][cs * 16 + lq * 4] = pk.ll;
  }
  __syncthreads();
  for (int it = 0; it < 2; ++it) {
    int l = tid + 256 * it;
    int dd = l >> 3, seg = l & 7;
    *(short8*)(attnT + ((size_t)b * PP + d0 + dd) * CC + h * DH + seg * 8) =
        *(const short8*)&O_l[dd][seg * 8];
  }
}

// ------------- Kernel 4: proj GEMM + bias + residual (fp32 out) ------------
__global__ __launch_bounds__(256) void proj_gemm(
    const unsigned short* __restrict__ attnT, const unsigned short* __restrict__ pwbf,
    const float* __restrict__ projb, const float* __restrict__ x,
    float* __restrict__ out) {
  int p0 = blockIdx.x * 128, o0 = blockIdx.y * 64, b = blockIdx.z;
  int tid = threadIdx.x;
  int w = tid >> 6, lane = tid & 63, lq = lane >> 4, ln = lane & 15;
  __shared__ unsigned short A_l[64][40];
  __shared__ unsigned short B_l[128][40];
  f32x4 acc[4][2];
  for (int i = 0; i < 4; ++i)
    for (int j = 0; j < 2; ++j) acc[i][j] = (f32x4){0.f, 0.f, 0.f, 0.f};
  for (int kc = 0; kc < 256; kc += 32) {
    {
      int row = tid >> 2, seg = tid & 3;
      *(short8*)&A_l[row][seg * 8] =
          *(const short8*)(pwbf + (size_t)(o0 + row) * CC + kc + seg * 8);
    }
    for (int it = 0; it < 2; ++it) {
      int l = tid + 256 * it;
      int row = l >> 2, seg = l & 3;
      *(short8*)&B_l[row][seg * 8] =
          *(const short8*)(attnT + ((size_t)b * PP + p0 + row) * CC + kc + seg * 8);
    }
    __syncthreads();
    short8 af[4], bfr[2];
    for (int i = 0; i < 4; ++i)
      af[i] = *(const short8*)&A_l[i * 16 + ln][lq * 8];
    for (int j = 0; j < 2; ++j)
      bfr[j] = *(const short8*)&B_l[w * 32 + j * 16 + ln][lq * 8];
    for (int i = 0; i < 4; ++i)
      for (int j = 0; j < 2; ++j) acc[i][j] = mfma16(af[i], bfr[j], acc[i][j]);
    __syncthreads();
  }
  for (int i = 0; i < 4; ++i) {
    for (int j = 0; j < 2; ++j) {
      int p = p0 + w * 32 + j * 16 + ln;
      for (int r = 0; r < 4; ++r) {
        int o = o0 + i * 16 + lq * 4 + r;
        size_t idx = ((size_t)b * CC + o) * PP + p;
        out[idx] = x[idx] + projb[o] + acc[i][j][r];
      }
    }
  }
}

// ---------------------------------------------------------------------------
extern "C" void kernel_launch(void* const* d_in, const int* in_sizes, int n_in,
                              void* d_out, int out_size, void* d_ws, size_t ws_size,
                              hipStream_t stream) {
  const float* x = (const float*)d_in[0];
  const float* gamma = (const float*)d_in[1];
  const float* beta = (const float*)d_in[2];
  const float* qkvw = (const float*)d_in[3];
  const float* qkvb = (const float*)d_in[4];
  const float* projw = (const float*)d_in[5];
  const float* projb = (const float*)d_in[6];
  float* out = (float*)d_out;
  char* ws = (char*)d_ws;

  float2* part = (float2*)(ws + 0);                        //  4 KB
  unsigned short* wall = (unsigned short*)(ws + 4210688);  // 512 KB
  unsigned short* pwbf = wall + 768 * 256;
  unsigned short* qb = (unsigned short*)(ws + 4734976);      // 4 MB
  unsigned short* kb = (unsigned short*)(ws + 8929280);      // 4 MB
  unsigned short* vT = (unsigned short*)(ws + 13123584);     // 4 MB
  unsigned short* attnT = (unsigned short*)(ws + 17317888);  // 4 MB

  prep<<<768, 256, 0, stream>>>(x, part, qkvw, projw, wall);
  nqkv<<<dim3(8, 6, 8), 256, 0, stream>>>(x, part, gamma, beta, wall, qkvb,
                                          qb, kb, vT);
  attn<<<dim3(16, 4, 8), 256, 0, stream>>>(qb, kb, vT, attnT);
  proj_gemm<<<dim3(8, 4, 8), 256, 0, stream>>>(attnT, pwbf, projb, x, out);
}

// Round 2
// 118.321 us; speedup vs baseline: 1.0396x; 1.0114x over previous
//
#include <hip/hip_runtime.h>
#include <stdint.h>

typedef __attribute__((ext_vector_type(8))) short short8;
typedef __attribute__((ext_vector_type(4))) float f32x4;
typedef __attribute__((ext_vector_type(16))) float f32x16;
typedef unsigned long long u64;

#define BB 8
#define CC 256
#define PP 1024
#define NH 4
#define DH 64

// q-scale: dh^-0.5 * log2(e), so softmax can use raw v_exp (exp2)
#define QSCALE 0.18033688f

__device__ __forceinline__ unsigned short f2bf(float f) {
  union { float f; unsigned u; } v; v.f = f;
  unsigned r = v.u + 0x7FFFu + ((v.u >> 16) & 1u);
  return (unsigned short)(r >> 16);
}

__device__ __forceinline__ f32x4 mfma16(short8 a, short8 b, f32x4 c) {
  return __builtin_amdgcn_mfma_f32_16x16x32_bf16(a, b, c, 0, 0, 0);
}
__device__ __forceinline__ f32x16 mfma32(short8 a, short8 b, f32x16 c) {
  return __builtin_amdgcn_mfma_f32_32x32x16_bf16(a, b, c, 0, 0, 0);
}

// -------- Kernel 1: GroupNorm partial sums (512 blk) + weight cvt (256 blk) -
__global__ __launch_bounds__(256) void prep(
    const float* __restrict__ x, float2* __restrict__ part,
    const float* __restrict__ qkvw, const float* __restrict__ projw,
    unsigned short* __restrict__ wall) {
  int blk = blockIdx.x;
  int tid = threadIdx.x;
  if (blk < 512) {
    int sl = blk & 7, g = (blk >> 3) & 7, b = blk >> 6;
    const float4* xb =
        (const float4*)(x + (size_t)(b * CC + g * 32) * PP) + sl * 1024;
    float s = 0.f, q = 0.f;
    for (int i = tid; i < 1024; i += 256) {
      float4 v = xb[i];
      s += v.x + v.y + v.z + v.w;
      q += v.x * v.x + v.y * v.y + v.z * v.z + v.w * v.w;
    }
    for (int off = 32; off > 0; off >>= 1) {
      s += __shfl_down(s, off);
      q += __shfl_down(q, off);
    }
    __shared__ float rs[4], rq[4];
    int w = tid >> 6;
    if ((tid & 63) == 0) { rs[w] = s; rq[w] = q; }
    __syncthreads();
    if (tid == 0)
      part[blk] = make_float2(rs[0] + rs[1] + rs[2] + rs[3],
                              rq[0] + rq[1] + rq[2] + rq[3]);
  } else {
    int i4 = (blk - 512) * 256 + tid;  // 65536 float4s total
    float4 v = (i4 < 49152) ? ((const float4*)qkvw)[i4]
                            : ((const float4*)projw)[i4 - 49152];
    ushort4 o;
    o.x = f2bf(v.x); o.y = f2bf(v.y); o.z = f2bf(v.z); o.w = f2bf(v.w);
    ((ushort4*)wall)[i4] = o;
  }
}

// ------------- Kernel 2: fused GroupNorm + QKV GEMM ------------------------
__global__ __launch_bounds__(256) void nqkv(
    const float* __restrict__ x, const float2* __restrict__ part,
    const float* __restrict__ gamma, const float* __restrict__ beta,
    const unsigned short* __restrict__ wbf, const float* __restrict__ qkvb,
    unsigned short* __restrict__ qb, unsigned short* __restrict__ kb,
    unsigned short* __restrict__ vT) {
  int p0 = blockIdx.x * 128, o0 = blockIdx.y * 128, b = blockIdx.z;
  int tid = threadIdx.x;
  int w = tid >> 6, lane = tid & 63, lq = lane >> 4, ln = lane & 15;
  int wy = w >> 1, wx = w & 1;
  __shared__ unsigned short A_l[128][40];
  __shared__ unsigned short B_l[128][40];
  __shared__ float scs[256], shs[256];
  __shared__ float g_m[8], g_r[8];
  if (tid < 8) {
    float S = 0.f, Q = 0.f;
    for (int i = 0; i < 8; ++i) {
      float2 pp = part[b * 64 + tid * 8 + i];
      S += pp.x; Q += pp.y;
    }
    float mean = S * (1.f / 32768.f);
    float var = Q * (1.f / 32768.f) - mean * mean;
    g_m[tid] = mean;
    g_r[tid] = rsqrtf(var + 1e-5f);
  }
  __syncthreads();
  {
    int c = tid;
    float sc = g_r[c >> 5] * gamma[c];
    scs[c] = sc;
    shs[c] = beta[c] - g_m[c >> 5] * sc;
  }
  __syncthreads();
  f32x4 acc[4][4];
  for (int i = 0; i < 4; ++i)
    for (int j = 0; j < 4; ++j) acc[i][j] = (f32x4){0.f, 0.f, 0.f, 0.f};
  int cc = tid >> 3, ps = tid & 7;
  for (int kc = 0; kc < 256; kc += 32) {
    {
      float sc = scs[kc + cc], sh = shs[kc + cc];
      const float* xr = x + ((size_t)(b * CC + kc + cc)) * PP + p0;
#pragma unroll
      for (int i = 0; i < 4; ++i) {
        int p = ps * 4 + 32 * i;
        float4 v = *(const float4*)(xr + p);
        A_l[p + 0][cc] = f2bf(v.x * sc + sh);
        A_l[p + 1][cc] = f2bf(v.y * sc + sh);
        A_l[p + 2][cc] = f2bf(v.z * sc + sh);
        A_l[p + 3][cc] = f2bf(v.w * sc + sh);
      }
    }
    for (int it = 0; it < 2; ++it) {
      int l = tid + 256 * it;
      int row = l >> 2, seg = l & 3;
      *(short8*)&B_l[row][seg * 8] =
          *(const short8*)(wbf + (size_t)(o0 + row) * CC + kc + seg * 8);
    }
    __syncthreads();
    short8 af[4], bfr[4];
    for (int i = 0; i < 4; ++i)
      af[i] = *(const short8*)&A_l[wy * 64 + i * 16 + ln][lq * 8];
    for (int j = 0; j < 4; ++j)
      bfr[j] = *(const short8*)&B_l[wx * 64 + j * 16 + ln][lq * 8];
    for (int i = 0; i < 4; ++i)
      for (int j = 0; j < 4; ++j) acc[i][j] = mfma16(af[i], bfr[j], acc[i][j]);
    __syncthreads();
  }
  for (int i = 0; i < 4; ++i) {
    for (int j = 0; j < 4; ++j) {
      int o = o0 + wx * 64 + j * 16 + ln;
      int s = o >> 8, h = (o >> 6) & 3, ch = o & 63;
      float bias = qkvb[o];
      float mul = (s == 0) ? QSCALE : 1.0f;
      size_t bh = (size_t)b * NH + h;
      int pbase = p0 + wy * 64 + i * 16 + lq * 4;
      if (s == 2) {
        union { unsigned short u[4]; u64 ll; } pk;
#pragma unroll
        for (int r = 0; r < 4; ++r) pk.u[r] = f2bf(acc[i][j][r] + bias);
        *(u64*)(vT + (bh * DH + ch) * PP + pbase) = pk.ll;
      } else {
        unsigned short* dst = (s == 0) ? qb : kb;
#pragma unroll
        for (int r = 0; r < 4; ++r)
          dst[(bh * PP + pbase + r) * DH + ch] =
              f2bf((acc[i][j][r] + bias) * mul);
      }
    }
  }
}

// ------------- Kernel 3: flash attention, 32x32 MFMA -----------------------
// 4 waves = (wd: d-half of 32) x (we: e-half of 64 per 128-iter).
// S^T = K Q^T via mfma_32x32x16: D col = d (lane&31), row = e-local
//   (r&3)+8*(r>>2)+4*hi. Softmax in-register; P NEVER touches LDS:
// V columns are stored sigma-PERMUTED (within each 16-col block:
//   {0-3}->{0-3}, {4-7}->{8-11}, {8-11}->{4-7}, {12-15}->{12-15}) so that
//   PV's B-fragment slot k (= hi*8+j) is exactly register 8c+j of the S^T
//   accumulator -> P fragments are own-lane, consecutive-register b64 pairs.
// K_l/V_l linear tiles with 8-short XOR swizzle (cb ^= row&7): bank-free.
// Cross-e-half O and row-sum reduced once at end via f32 LDS staging.
__global__ __launch_bounds__(256, 2) void attn(
    const unsigned short* __restrict__ qb, const unsigned short* __restrict__ kb,
    const unsigned short* __restrict__ vT, unsigned short* __restrict__ attnT) {
  int d0 = blockIdx.x * 64, h = blockIdx.y, b = blockIdx.z;
  int tid = threadIdx.x;
  int w = tid >> 6, lane = tid & 63;
  int n = lane & 31, hi = lane >> 5;
  int wd = w & 1, we = w >> 1;
  size_t bh = (size_t)b * NH + h;
  const unsigned short* qbase = qb + bh * PP * DH;
  const unsigned short* kbase = kb + bh * PP * DH;
  const unsigned short* vbase = vT + bh * DH * PP;

  __shared__ __align__(16) char smem[32768];
  unsigned short* K_ls = (unsigned short*)smem;            // [128][64] swz
  unsigned short* V_ls = (unsigned short*)(smem + 16384);  // [64][128] swz
  float* Ored = (float*)smem;                              // [128][34]
  float* lsred = (float*)(smem + 17408);                   // [64]
  unsigned short* O_l = (unsigned short*)(smem + 17664);   // [64][72]

#define KIDX(e, cb) ((e) * 64 + (((cb) ^ ((e) & 7)) << 3))
#define VIDX(ch, cb, off) ((ch) * 128 + (((cb) ^ ((ch) & 7)) << 3) + (off))

  int ke = tid >> 1, kseg = tid & 1;   // K: 128 rows x 2 half-rows
  int vch = tid >> 2, vseg = tid & 3;  // V: 64 rows x 4 quarter-rows

  short8 qf[4];
  {
    int dq = d0 + wd * 32 + n;
#pragma unroll
    for (int kc = 0; kc < 4; ++kc)
      qf[kc] = *(const short8*)(qbase + (size_t)dq * DH + kc * 16 + hi * 8);
  }
  float l_sum = 0.f;
  f32x16 o_acc[2];
#pragma unroll
  for (int i = 0; i < 16; ++i) { o_acc[0][i] = 0.f; o_acc[1][i] = 0.f; }

  short8 kr[4], vr[4];
#pragma unroll
  for (int i = 0; i < 4; ++i)
    kr[i] = *(const short8*)(kbase + (size_t)ke * DH + kseg * 32 + i * 8);
#pragma unroll
  for (int i = 0; i < 4; ++i)
    vr[i] = *(const short8*)(vbase + (size_t)vch * PP + vseg * 32 + i * 8);

  for (int e0 = 0; e0 < PP; e0 += 128) {
    // ---- stage K (b128, swizzled) ----
#pragma unroll
    for (int i = 0; i < 4; ++i)
      *(short8*)&K_ls[KIDX(ke, kseg * 4 + i)] = kr[i];
    // ---- stage V (2x b64, sigma-permuted + swizzled) ----
#pragma unroll
    for (int i = 0; i < 4; ++i) {
      int acb = vseg * 4 + i;     // actual 8-col chunk (0..15)
      int blkA = acb >> 1;        // 16-col block
      int h8 = acb & 1;
      union { short8 v; u64 q[2]; } uv; uv.v = vr[i];
      *(u64*)&V_ls[VIDX(vch, blkA * 2 + 0, h8 * 4)] = uv.q[0];
      *(u64*)&V_ls[VIDX(vch, blkA * 2 + 1, h8 * 4)] = uv.q[1];
    }
    if (e0 + 128 < PP) {
      int en = e0 + 128;
#pragma unroll
      for (int i = 0; i < 4; ++i)
        kr[i] = *(const short8*)(kbase + (size_t)(en + ke) * DH + kseg * 32 + i * 8);
#pragma unroll
      for (int i = 0; i < 4; ++i)
        vr[i] = *(const short8*)(vbase + (size_t)vch * PP + en + vseg * 32 + i * 8);
    }
    __syncthreads();
    // ---- QK^T (S^T) + softmax, per 32-e tile ----
    u64 pk[2][4];
#pragma unroll
    for (int t = 0; t < 2; ++t) {
      f32x16 s;
#pragma unroll
      for (int i = 0; i < 16; ++i) s[i] = 0.f;
      int erow = we * 64 + t * 32 + n;
#pragma unroll
      for (int kc = 0; kc < 4; ++kc) {
        short8 af = *(const short8*)&K_ls[KIDX(erow, kc * 2 + hi)];
        s = mfma32(af, qf[kc], s);
      }
#pragma unroll
      for (int g = 0; g < 4; ++g) {
        float p0 = __builtin_amdgcn_exp2f(fminf(s[4 * g + 0], 86.f));
        float p1 = __builtin_amdgcn_exp2f(fminf(s[4 * g + 1], 86.f));
        float p2 = __builtin_amdgcn_exp2f(fminf(s[4 * g + 2], 86.f));
        float p3 = __builtin_amdgcn_exp2f(fminf(s[4 * g + 3], 86.f));
        l_sum += (p0 + p1) + (p2 + p3);
        union { unsigned short u[4]; u64 ll; } pkk;
        pkk.u[0] = f2bf(p0); pkk.u[1] = f2bf(p1);
        pkk.u[2] = f2bf(p2); pkk.u[3] = f2bf(p3);
        pk[t][g] = pkk.ll;
      }
    }
    // ---- PV: O[ch][d] += V_sigma * P (P fragment = own regs) ----
#pragma unroll
    for (int t = 0; t < 2; ++t) {
#pragma unroll
      for (int c = 0; c < 2; ++c) {
        union { u64 q[2]; short8 v; } pf;
        pf.q[0] = pk[t][2 * c];
        pf.q[1] = pk[t][2 * c + 1];
        int cb = we * 8 + t * 4 + c * 2 + hi;
#pragma unroll
        for (int mt = 0; mt < 2; ++mt) {
          int ch = mt * 32 + n;
          short8 af = *(const short8*)&V_ls[VIDX(ch, cb, 0)];
          o_acc[mt] = mfma32(af, pf.v, o_acc[mt]);
        }
      }
    }
    __syncthreads();
  }
  // ---- cross-hi row-sum, then cross-we reduce via LDS ----
  l_sum += __shfl_xor(l_sum, 32);
  if (we == 1) {
    if (hi == 0) lsred[wd * 32 + n] = l_sum;
#pragma unroll
    for (int mt = 0; mt < 2; ++mt)
#pragma unroll
      for (int r = 0; r < 16; ++r) {
        int chl = (r & 3) + 8 * (r >> 2) + 4 * hi;
        Ored[(wd * 64 + mt * 32 + chl) * 34 + n] = o_acc[mt][r];
      }
  }
  __syncthreads();
  if (we == 0) {
    float inv = 1.f / (l_sum + lsred[wd * 32 + n]);
#pragma unroll
    for (int mt = 0; mt < 2; ++mt) {
#pragma unroll
      for (int g = 0; g < 4; ++g) {
        union { unsigned short u[4]; u64 ll; } pkk;
#pragma unroll
        for (int q = 0; q < 4; ++q) {
          int r = g * 4 + q;
          int chl = q + 8 * g + 4 * hi;
          float v = (o_acc[mt][r] + Ored[(wd * 64 + mt * 32 + chl) * 34 + n]) * inv;
          pkk.u[q] = f2bf(v);
        }
        *(u64*)&O_l[(wd * 32 + n) * 72 + mt * 32 + g * 8 + 4 * hi] = pkk.ll;
      }
    }
  }
  __syncthreads();
  for (int it = 0; it < 2; ++it) {
    int l2 = tid + 256 * it;
    int dd = l2 >> 3, seg = l2 & 7;
    *(short8*)(attnT + ((size_t)b * PP + d0 + dd) * CC + h * DH + seg * 8) =
        *(const short8*)&O_l[dd * 72 + seg * 8];
  }
#undef KIDX
#undef VIDX
}

// ------------- Kernel 4: proj GEMM + bias + residual (fp32 out) ------------
__global__ __launch_bounds__(256) void proj_gemm(
    const unsigned short* __restrict__ attnT, const unsigned short* __restrict__ pwbf,
    const float* __restrict__ projb, const float* __restrict__ x,
    float* __restrict__ out) {
  int p0 = blockIdx.x * 128, o0 = blockIdx.y * 64, b = blockIdx.z;
  int tid = threadIdx.x;
  int w = tid >> 6, lane = tid & 63, lq = lane >> 4, ln = lane & 15;
  __shared__ unsigned short A_l[64][40];
  __shared__ unsigned short B_l[128][40];
  f32x4 acc[4][2];
  for (int i = 0; i < 4; ++i)
    for (int j = 0; j < 2; ++j) acc[i][j] = (f32x4){0.f, 0.f, 0.f, 0.f};
  for (int kc = 0; kc < 256; kc += 32) {
    {
      int row = tid >> 2, seg = tid & 3;
      *(short8*)&A_l[row][seg * 8] =
          *(const short8*)(pwbf + (size_t)(o0 + row) * CC + kc + seg * 8);
    }
    for (int it = 0; it < 2; ++it) {
      int l = tid + 256 * it;
      int row = l >> 2, seg = l & 3;
      *(short8*)&B_l[row][seg * 8] =
          *(const short8*)(attnT + ((size_t)b * PP + p0 + row) * CC + kc + seg * 8);
    }
    __syncthreads();
    short8 af[4], bfr[2];
    for (int i = 0; i < 4; ++i)
      af[i] = *(const short8*)&A_l[i * 16 + ln][lq * 8];
    for (int j = 0; j < 2; ++j)
      bfr[j] = *(const short8*)&B_l[w * 32 + j * 16 + ln][lq * 8];
    for (int i = 0; i < 4; ++i)
      for (int j = 0; j < 2; ++j) acc[i][j] = mfma16(af[i], bfr[j], acc[i][j]);
    __syncthreads();
  }
  for (int i = 0; i < 4; ++i) {
    for (int j = 0; j < 2; ++j) {
      int p = p0 + w * 32 + j * 16 + ln;
      for (int r = 0; r < 4; ++r) {
        int o = o0 + i * 16 + lq * 4 + r;
        size_t idx = ((size_t)b * CC + o) * PP + p;
        out[idx] = x[idx] + projb[o] + acc[i][j][r];
      }
    }
  }
}

// ---------------------------------------------------------------------------
extern "C" void kernel_launch(void* const* d_in, const int* in_sizes, int n_in,
                              void* d_out, int out_size, void* d_ws, size_t ws_size,
                              hipStream_t stream) {
  const float* x = (const float*)d_in[0];
  const float* gamma = (const float*)d_in[1];
  const float* beta = (const float*)d_in[2];
  const float* qkvw = (const float*)d_in[3];
  const float* qkvb = (const float*)d_in[4];
  const float* projw = (const float*)d_in[5];
  const float* projb = (const float*)d_in[6];
  float* out = (float*)d_out;
  char* ws = (char*)d_ws;

  float2* part = (float2*)(ws + 0);                        //  4 KB
  unsigned short* wall = (unsigned short*)(ws + 4210688);  // 512 KB
  unsigned short* pwbf = wall + 768 * 256;
  unsigned short* qb = (unsigned short*)(ws + 4734976);      // 4 MB
  unsigned short* kb = (unsigned short*)(ws + 8929280);      // 4 MB
  unsigned short* vT = (unsigned short*)(ws + 13123584);     // 4 MB
  unsigned short* attnT = (unsigned short*)(ws + 17317888);  // 4 MB

  prep<<<768, 256, 0, stream>>>(x, part, qkvw, projw, wall);
  nqkv<<<dim3(8, 6, 8), 256, 0, stream>>>(x, part, gamma, beta, wall, qkvb,
                                          qb, kb, vT);
  attn<<<dim3(16, 4, 8), 256, 0, stream>>>(qb, kb, vT, attnT);
  proj_gemm<<<dim3(8, 4, 8), 256, 0, stream>>>(attnT, pwbf, projb, x, out);
}

// Round 3
// 117.129 us; speedup vs baseline: 1.0502x; 1.0102x over previous
//
#include <hip/hip_runtime.h>
#include <stdint.h>

typedef __attribute__((ext_vector_type(8))) short short8;
typedef __attribute__((ext_vector_type(4))) float f32x4;
typedef __attribute__((ext_vector_type(16))) float f32x16;
typedef unsigned long long u64;

#define BB 8
#define CC 256
#define PP 1024
#define NH 4
#define DH 64

// q-scale: dh^-0.5 * log2(e), so softmax can use raw v_exp (exp2)
#define QSCALE 0.18033688f

__device__ __forceinline__ unsigned short f2bf(float f) {
  union { float f; unsigned u; } v; v.f = f;
  unsigned r = v.u + 0x7FFFu + ((v.u >> 16) & 1u);
  return (unsigned short)(r >> 16);
}

__device__ __forceinline__ f32x4 mfma16(short8 a, short8 b, f32x4 c) {
  return __builtin_amdgcn_mfma_f32_16x16x32_bf16(a, b, c, 0, 0, 0);
}
__device__ __forceinline__ f32x16 mfma32(short8 a, short8 b, f32x16 c) {
  return __builtin_amdgcn_mfma_f32_32x32x16_bf16(a, b, c, 0, 0, 0);
}

// -------- Kernel 1: GroupNorm partial sums (512 blk) + weight cvt (256 blk) -
__global__ __launch_bounds__(256) void prep(
    const float* __restrict__ x, float2* __restrict__ part,
    const float* __restrict__ qkvw, const float* __restrict__ projw,
    unsigned short* __restrict__ wall) {
  int blk = blockIdx.x;
  int tid = threadIdx.x;
  if (blk < 512) {
    int sl = blk & 7, g = (blk >> 3) & 7, b = blk >> 6;
    const float4* xb =
        (const float4*)(x + (size_t)(b * CC + g * 32) * PP) + sl * 1024;
    float s = 0.f, q = 0.f;
    for (int i = tid; i < 1024; i += 256) {
      float4 v = xb[i];
      s += v.x + v.y + v.z + v.w;
      q += v.x * v.x + v.y * v.y + v.z * v.z + v.w * v.w;
    }
    for (int off = 32; off > 0; off >>= 1) {
      s += __shfl_down(s, off);
      q += __shfl_down(q, off);
    }
    __shared__ float rs[4], rq[4];
    int w = tid >> 6;
    if ((tid & 63) == 0) { rs[w] = s; rq[w] = q; }
    __syncthreads();
    if (tid == 0)
      part[blk] = make_float2(rs[0] + rs[1] + rs[2] + rs[3],
                              rq[0] + rq[1] + rq[2] + rq[3]);
  } else {
    int i4 = (blk - 512) * 256 + tid;  // 65536 float4s total
    float4 v = (i4 < 49152) ? ((const float4*)qkvw)[i4]
                            : ((const float4*)projw)[i4 - 49152];
    ushort4 o;
    o.x = f2bf(v.x); o.y = f2bf(v.y); o.z = f2bf(v.z); o.w = f2bf(v.w);
    ((ushort4*)wall)[i4] = o;
  }
}

// ------------- Kernel 2: fused GroupNorm + QKV GEMM ------------------------
// Grid linearized 384; decode keeps the 6 o-tiles sharing one (p0,b) x-slice
// on the SAME XCD (bid mod 8 constant within group) -> x re-reads hit L2.
// A_l padded to 42 shorts/row: ds_write_b16 transpose becomes bank-free
// (row-pair stride 42*4=84 dwords, 84*? mod 32 distinct for all 8 ps).
__global__ __launch_bounds__(256) void nqkv(
    const float* __restrict__ x, const float2* __restrict__ part,
    const float* __restrict__ gamma, const float* __restrict__ beta,
    const unsigned short* __restrict__ wbf, const float* __restrict__ qkvb,
    unsigned short* __restrict__ qb, unsigned short* __restrict__ kb,
    unsigned short* __restrict__ vT) {
  int bid = blockIdx.x;
  int c8 = bid & 7, rr = bid >> 3;       // rr: 0..47
  int t = rr % 6, base = rr / 6;         // t: o-tile, base: 0..7
  int pb = base * 8 + c8;                // 0..63, same-XCD within o-group
  int p0 = (pb >> 3) * 128, b = pb & 7, o0 = t * 128;
  int tid = threadIdx.x;
  int w = tid >> 6, lane = tid & 63, lq = lane >> 4, ln = lane & 15;
  int wy = w >> 1, wx = w & 1;
  __shared__ unsigned short A_l[128][42];
  __shared__ unsigned short B_l[128][40];
  __shared__ float scs[256], shs[256];
  __shared__ float g_m[8], g_r[8];
  if (tid < 8) {
    float S = 0.f, Q = 0.f;
    for (int i = 0; i < 8; ++i) {
      float2 pp = part[b * 64 + tid * 8 + i];
      S += pp.x; Q += pp.y;
    }
    float mean = S * (1.f / 32768.f);
    float var = Q * (1.f / 32768.f) - mean * mean;
    g_m[tid] = mean;
    g_r[tid] = rsqrtf(var + 1e-5f);
  }
  __syncthreads();
  {
    int c = tid;
    float sc = g_r[c >> 5] * gamma[c];
    scs[c] = sc;
    shs[c] = beta[c] - g_m[c >> 5] * sc;
  }
  __syncthreads();
  f32x4 acc[4][4];
  for (int i = 0; i < 4; ++i)
    for (int j = 0; j < 4; ++j) acc[i][j] = (f32x4){0.f, 0.f, 0.f, 0.f};
  int cc = tid >> 3, ps = tid & 7;
  for (int kc = 0; kc < 256; kc += 32) {
    {
      float sc = scs[kc + cc], sh = shs[kc + cc];
      const float* xr = x + ((size_t)(b * CC + kc + cc)) * PP + p0;
#pragma unroll
      for (int i = 0; i < 4; ++i) {
        int p = ps * 4 + 32 * i;
        float4 v = *(const float4*)(xr + p);
        A_l[p + 0][cc] = f2bf(v.x * sc + sh);
        A_l[p + 1][cc] = f2bf(v.y * sc + sh);
        A_l[p + 2][cc] = f2bf(v.z * sc + sh);
        A_l[p + 3][cc] = f2bf(v.w * sc + sh);
      }
    }
    for (int it = 0; it < 2; ++it) {
      int l = tid + 256 * it;
      int row = l >> 2, seg = l & 3;
      *(short8*)&B_l[row][seg * 8] =
          *(const short8*)(wbf + (size_t)(o0 + row) * CC + kc + seg * 8);
    }
    __syncthreads();
    short8 af[4], bfr[4];
    for (int i = 0; i < 4; ++i)
      af[i] = *(const short8*)&A_l[wy * 64 + i * 16 + ln][lq * 8];
    for (int j = 0; j < 4; ++j)
      bfr[j] = *(const short8*)&B_l[wx * 64 + j * 16 + ln][lq * 8];
    for (int i = 0; i < 4; ++i)
      for (int j = 0; j < 4; ++j) acc[i][j] = mfma16(af[i], bfr[j], acc[i][j]);
    __syncthreads();
  }
  for (int i = 0; i < 4; ++i) {
    for (int j = 0; j < 4; ++j) {
      int o = o0 + wx * 64 + j * 16 + ln;
      int s = o >> 8, h = (o >> 6) & 3, ch = o & 63;
      float bias = qkvb[o];
      float mul = (s == 0) ? QSCALE : 1.0f;
      size_t bh = (size_t)b * NH + h;
      int pbase = p0 + wy * 64 + i * 16 + lq * 4;
      if (s == 2) {
        union { unsigned short u[4]; u64 ll; } pk;
#pragma unroll
        for (int r = 0; r < 4; ++r) pk.u[r] = f2bf(acc[i][j][r] + bias);
        *(u64*)(vT + (bh * DH + ch) * PP + pbase) = pk.ll;
      } else {
        unsigned short* dst = (s == 0) ? qb : kb;
#pragma unroll
        for (int r = 0; r < 4; ++r)
          dst[(bh * PP + pbase + r) * DH + ch] =
              f2bf((acc[i][j][r] + bias) * mul);
      }
    }
  }
}

// ------------- Kernel 3: flash attention, 32x32 MFMA -----------------------
// Grid linearized 512; decode keeps the 16 d-tiles sharing one (h,b) K/V
// (256 KB) on the SAME XCD -> 16x K/V re-reads served from that L2 instead
// of L3/HBM (was ~128 MB of cross-die traffic).
__global__ __launch_bounds__(256, 2) void attn(
    const unsigned short* __restrict__ qb, const unsigned short* __restrict__ kb,
    const unsigned short* __restrict__ vT, unsigned short* __restrict__ attnT) {
  int bid = blockIdx.x;
  int c8 = bid & 7, rr = bid >> 3;   // rr: 0..63
  int t16 = rr & 15, base = rr >> 4; // t16: d-tile, base: 0..3
  int g = base * 8 + c8;             // 0..31 (h,b) group, same XCD
  int h = g & 3, b = g >> 2;
  int d0 = t16 * 64;
  int tid = threadIdx.x;
  int w = tid >> 6, lane = tid & 63;
  int n = lane & 31, hi = lane >> 5;
  int wd = w & 1, we = w >> 1;
  size_t bh = (size_t)b * NH + h;
  const unsigned short* qbase = qb + bh * PP * DH;
  const unsigned short* kbase = kb + bh * PP * DH;
  const unsigned short* vbase = vT + bh * DH * PP;

  __shared__ __align__(16) char smem[32768];
  unsigned short* K_ls = (unsigned short*)smem;            // [128][64] swz
  unsigned short* V_ls = (unsigned short*)(smem + 16384);  // [64][128] swz
  float* Ored = (float*)smem;                              // [128][34]
  float* lsred = (float*)(smem + 17408);                   // [64]
  unsigned short* O_l = (unsigned short*)(smem + 17664);   // [64][72]

#define KIDX(e, cb) ((e) * 64 + (((cb) ^ ((e) & 7)) << 3))
#define VIDX(ch, cb, off) ((ch) * 128 + (((cb) ^ ((ch) & 7)) << 3) + (off))

  int ke = tid >> 1, kseg = tid & 1;   // K: 128 rows x 2 half-rows
  int vch = tid >> 2, vseg = tid & 3;  // V: 64 rows x 4 quarter-rows

  short8 qf[4];
  {
    int dq = d0 + wd * 32 + n;
#pragma unroll
    for (int kc = 0; kc < 4; ++kc)
      qf[kc] = *(const short8*)(qbase + (size_t)dq * DH + kc * 16 + hi * 8);
  }
  float l_sum = 0.f;
  f32x16 o_acc[2];
#pragma unroll
  for (int i = 0; i < 16; ++i) { o_acc[0][i] = 0.f; o_acc[1][i] = 0.f; }

  short8 kr[4], vr[4];
#pragma unroll
  for (int i = 0; i < 4; ++i)
    kr[i] = *(const short8*)(kbase + (size_t)ke * DH + kseg * 32 + i * 8);
#pragma unroll
  for (int i = 0; i < 4; ++i)
    vr[i] = *(const short8*)(vbase + (size_t)vch * PP + vseg * 32 + i * 8);

  for (int e0 = 0; e0 < PP; e0 += 128) {
#pragma unroll
    for (int i = 0; i < 4; ++i)
      *(short8*)&K_ls[KIDX(ke, kseg * 4 + i)] = kr[i];
#pragma unroll
    for (int i = 0; i < 4; ++i) {
      int acb = vseg * 4 + i;     // actual 8-col chunk (0..15)
      int blkA = acb >> 1;        // 16-col block
      int h8 = acb & 1;
      union { short8 v; u64 q[2]; } uv; uv.v = vr[i];
      *(u64*)&V_ls[VIDX(vch, blkA * 2 + 0, h8 * 4)] = uv.q[0];
      *(u64*)&V_ls[VIDX(vch, blkA * 2 + 1, h8 * 4)] = uv.q[1];
    }
    if (e0 + 128 < PP) {
      int en = e0 + 128;
#pragma unroll
      for (int i = 0; i < 4; ++i)
        kr[i] = *(const short8*)(kbase + (size_t)(en + ke) * DH + kseg * 32 + i * 8);
#pragma unroll
      for (int i = 0; i < 4; ++i)
        vr[i] = *(const short8*)(vbase + (size_t)vch * PP + en + vseg * 32 + i * 8);
    }
    __syncthreads();
    u64 pk[2][4];
#pragma unroll
    for (int t = 0; t < 2; ++t) {
      f32x16 s;
#pragma unroll
      for (int i = 0; i < 16; ++i) s[i] = 0.f;
      int erow = we * 64 + t * 32 + n;
#pragma unroll
      for (int kc = 0; kc < 4; ++kc) {
        short8 af = *(const short8*)&K_ls[KIDX(erow, kc * 2 + hi)];
        s = mfma32(af, qf[kc], s);
      }
#pragma unroll
      for (int gg = 0; gg < 4; ++gg) {
        float p0 = __builtin_amdgcn_exp2f(fminf(s[4 * gg + 0], 86.f));
        float p1 = __builtin_amdgcn_exp2f(fminf(s[4 * gg + 1], 86.f));
        float p2 = __builtin_amdgcn_exp2f(fminf(s[4 * gg + 2], 86.f));
        float p3 = __builtin_amdgcn_exp2f(fminf(s[4 * gg + 3], 86.f));
        l_sum += (p0 + p1) + (p2 + p3);
        union { unsigned short u[4]; u64 ll; } pkk;
        pkk.u[0] = f2bf(p0); pkk.u[1] = f2bf(p1);
        pkk.u[2] = f2bf(p2); pkk.u[3] = f2bf(p3);
        pk[t][gg] = pkk.ll;
      }
    }
#pragma unroll
    for (int t = 0; t < 2; ++t) {
#pragma unroll
      for (int c = 0; c < 2; ++c) {
        union { u64 q[2]; short8 v; } pf;
        pf.q[0] = pk[t][2 * c];
        pf.q[1] = pk[t][2 * c + 1];
        int cb = we * 8 + t * 4 + c * 2 + hi;
#pragma unroll
        for (int mt = 0; mt < 2; ++mt) {
          int ch = mt * 32 + n;
          short8 af = *(const short8*)&V_ls[VIDX(ch, cb, 0)];
          o_acc[mt] = mfma32(af, pf.v, o_acc[mt]);
        }
      }
    }
    __syncthreads();
  }
  l_sum += __shfl_xor(l_sum, 32);
  if (we == 1) {
    if (hi == 0) lsred[wd * 32 + n] = l_sum;
#pragma unroll
    for (int mt = 0; mt < 2; ++mt)
#pragma unroll
      for (int r = 0; r < 16; ++r) {
        int chl = (r & 3) + 8 * (r >> 2) + 4 * hi;
        Ored[(wd * 64 + mt * 32 + chl) * 34 + n] = o_acc[mt][r];
      }
  }
  __syncthreads();
  if (we == 0) {
    float inv = 1.f / (l_sum + lsred[wd * 32 + n]);
#pragma unroll
    for (int mt = 0; mt < 2; ++mt) {
#pragma unroll
      for (int gg = 0; gg < 4; ++gg) {
        union { unsigned short u[4]; u64 ll; } pkk;
#pragma unroll
        for (int q = 0; q < 4; ++q) {
          int r = gg * 4 + q;
          int chl = q + 8 * gg + 4 * hi;
          float v = (o_acc[mt][r] + Ored[(wd * 64 + mt * 32 + chl) * 34 + n]) * inv;
          pkk.u[q] = f2bf(v);
        }
        *(u64*)&O_l[(wd * 32 + n) * 72 + mt * 32 + gg * 8 + 4 * hi] = pkk.ll;
      }
    }
  }
  __syncthreads();
  for (int it = 0; it < 2; ++it) {
    int l2 = tid + 256 * it;
    int dd = l2 >> 3, seg = l2 & 7;
    *(short8*)(attnT + ((size_t)b * PP + d0 + dd) * CC + h * DH + seg * 8) =
        *(const short8*)&O_l[dd * 72 + seg * 8];
  }
#undef KIDX
#undef VIDX
}

// ------------- Kernel 4: proj GEMM + bias + residual (fp32 out) ------------
// Grid linearized 256; 4 o-tiles sharing one (p0,b) attnT slice -> same XCD.
__global__ __launch_bounds__(256) void proj_gemm(
    const unsigned short* __restrict__ attnT, const unsigned short* __restrict__ pwbf,
    const float* __restrict__ projb, const float* __restrict__ x,
    float* __restrict__ out) {
  int bid = blockIdx.x;
  int c8 = bid & 7, rr = bid >> 3;   // rr: 0..31
  int t = rr & 3, base = rr >> 2;    // t: o-tile, base: 0..7
  int pb = base * 8 + c8;            // 0..63
  int p0 = (pb >> 3) * 128, b = pb & 7, o0 = t * 64;
  int tid = threadIdx.x;
  int w = tid >> 6, lane = tid & 63, lq = lane >> 4, ln = lane & 15;
  __shared__ unsigned short A_l[64][40];
  __shared__ unsigned short B_l[128][40];
  f32x4 acc[4][2];
  for (int i = 0; i < 4; ++i)
    for (int j = 0; j < 2; ++j) acc[i][j] = (f32x4){0.f, 0.f, 0.f, 0.f};
  for (int kc = 0; kc < 256; kc += 32) {
    {
      int row = tid >> 2, seg = tid & 3;
      *(short8*)&A_l[row][seg * 8] =
          *(const short8*)(pwbf + (size_t)(o0 + row) * CC + kc + seg * 8);
    }
    for (int it = 0; it < 2; ++it) {
      int l = tid + 256 * it;
      int row = l >> 2, seg = l & 3;
      *(short8*)&B_l[row][seg * 8] =
          *(const short8*)(attnT + ((size_t)b * PP + p0 + row) * CC + kc + seg * 8);
    }
    __syncthreads();
    short8 af[4], bfr[2];
    for (int i = 0; i < 4; ++i)
      af[i] = *(const short8*)&A_l[i * 16 + ln][lq * 8];
    for (int j = 0; j < 2; ++j)
      bfr[j] = *(const short8*)&B_l[w * 32 + j * 16 + ln][lq * 8];
    for (int i = 0; i < 4; ++i)
      for (int j = 0; j < 2; ++j) acc[i][j] = mfma16(af[i], bfr[j], acc[i][j]);
    __syncthreads();
  }
  for (int i = 0; i < 4; ++i) {
    for (int j = 0; j < 2; ++j) {
      int p = p0 + w * 32 + j * 16 + ln;
      for (int r = 0; r < 4; ++r) {
        int o = o0 + i * 16 + lq * 4 + r;
        size_t idx = ((size_t)b * CC + o) * PP + p;
        out[idx] = x[idx] + projb[o] + acc[i][j][r];
      }
    }
  }
}

// ---------------------------------------------------------------------------
extern "C" void kernel_launch(void* const* d_in, const int* in_sizes, int n_in,
                              void* d_out, int out_size, void* d_ws, size_t ws_size,
                              hipStream_t stream) {
  const float* x = (const float*)d_in[0];
  const float* gamma = (const float*)d_in[1];
  const float* beta = (const float*)d_in[2];
  const float* qkvw = (const float*)d_in[3];
  const float* qkvb = (const float*)d_in[4];
  const float* projw = (const float*)d_in[5];
  const float* projb = (const float*)d_in[6];
  float* out = (float*)d_out;
  char* ws = (char*)d_ws;

  float2* part = (float2*)(ws + 0);                        //  4 KB
  unsigned short* wall = (unsigned short*)(ws + 4210688);  // 512 KB
  unsigned short* pwbf = wall + 768 * 256;
  unsigned short* qb = (unsigned short*)(ws + 4734976);      // 4 MB
  unsigned short* kb = (unsigned short*)(ws + 8929280);      // 4 MB
  unsigned short* vT = (unsigned short*)(ws + 13123584);     // 4 MB
  unsigned short* attnT = (unsigned short*)(ws + 17317888);  // 4 MB

  prep<<<768, 256, 0, stream>>>(x, part, qkvw, projw, wall);
  nqkv<<<384, 256, 0, stream>>>(x, part, gamma, beta, wall, qkvb, qb, kb, vT);
  attn<<<512, 256, 0, stream>>>(qb, kb, vT, attnT);
  proj_gemm<<<256, 256, 0, stream>>>(attnT, pwbf, projb, x, out);
}

// Round 4
// 115.117 us; speedup vs baseline: 1.0686x; 1.0175x over previous
//
#include <hip/hip_runtime.h>
#include <stdint.h>

typedef __attribute__((ext_vector_type(8))) short short8;
typedef __attribute__((ext_vector_type(4))) float f32x4;
typedef __attribute__((ext_vector_type(16))) float f32x16;
typedef unsigned long long u64;

#define BB 8
#define CC 256
#define PP 1024
#define NH 4
#define DH 64

// q-scale: dh^-0.5 * log2(e), so softmax can use raw v_exp (exp2)
#define QSCALE 0.18033688f

__device__ __forceinline__ unsigned short f2bf(float f) {
  union { float f; unsigned u; } v; v.f = f;
  unsigned r = v.u + 0x7FFFu + ((v.u >> 16) & 1u);
  return (unsigned short)(r >> 16);
}

__device__ __forceinline__ f32x4 mfma16(short8 a, short8 b, f32x4 c) {
  return __builtin_amdgcn_mfma_f32_16x16x32_bf16(a, b, c, 0, 0, 0);
}
__device__ __forceinline__ f32x16 mfma32(short8 a, short8 b, f32x16 c) {
  return __builtin_amdgcn_mfma_f32_32x32x16_bf16(a, b, c, 0, 0, 0);
}

// -------- Kernel 1: GroupNorm partial sums (512 blk) + weight cvt (256 blk) -
__global__ __launch_bounds__(256) void prep(
    const float* __restrict__ x, float2* __restrict__ part,
    const float* __restrict__ qkvw, const float* __restrict__ projw,
    unsigned short* __restrict__ wall) {
  int blk = blockIdx.x;
  int tid = threadIdx.x;
  if (blk < 512) {
    int sl = blk & 7, g = (blk >> 3) & 7, b = blk >> 6;
    const float4* xb =
        (const float4*)(x + (size_t)(b * CC + g * 32) * PP) + sl * 1024;
    float s = 0.f, q = 0.f;
    for (int i = tid; i < 1024; i += 256) {
      float4 v = xb[i];
      s += v.x + v.y + v.z + v.w;
      q += v.x * v.x + v.y * v.y + v.z * v.z + v.w * v.w;
    }
    for (int off = 32; off > 0; off >>= 1) {
      s += __shfl_down(s, off);
      q += __shfl_down(q, off);
    }
    __shared__ float rs[4], rq[4];
    int w = tid >> 6;
    if ((tid & 63) == 0) { rs[w] = s; rq[w] = q; }
    __syncthreads();
    if (tid == 0)
      part[blk] = make_float2(rs[0] + rs[1] + rs[2] + rs[3],
                              rq[0] + rq[1] + rq[2] + rq[3]);
  } else {
    int i4 = (blk - 512) * 256 + tid;  // 65536 float4s total
    float4 v = (i4 < 49152) ? ((const float4*)qkvw)[i4]
                            : ((const float4*)projw)[i4 - 49152];
    ushort4 o;
    o.x = f2bf(v.x); o.y = f2bf(v.y); o.z = f2bf(v.z); o.w = f2bf(v.w);
    ((ushort4*)wall)[i4] = o;
  }
}

// ------------- Kernel 2: fused GroupNorm + QKV GEMM ------------------------
// Tile 64p x 128o -> grid 768 = exactly 3 blocks/CU (was 384 @ 2-cap = 75%
// machine util). launch_bounds(256,3) caps VGPR at 170 (acc is only 32).
// Decode keeps the 6 o-tiles sharing one (p0,b) x-slice on the SAME XCD;
// batch b = bid&7 pins x[b] (4 MB) to one XCD L2.
// A_l padded to 42 shorts/row: ds_write_b16 transpose is bank-conflict-free.
__global__ __launch_bounds__(256, 3) void nqkv(
    const float* __restrict__ x, const float2* __restrict__ part,
    const float* __restrict__ gamma, const float* __restrict__ beta,
    const unsigned short* __restrict__ wbf, const float* __restrict__ qkvb,
    unsigned short* __restrict__ qb, unsigned short* __restrict__ kb,
    unsigned short* __restrict__ vT) {
  int bid = blockIdx.x;
  int c8 = bid & 7, rr = bid >> 3;       // rr: 0..95
  int t = rr % 6, base = rr / 6;         // t: o-tile, base: 0..15
  int p0 = base * 64, b = c8, o0 = t * 128;
  int tid = threadIdx.x;
  int w = tid >> 6, lane = tid & 63, lq = lane >> 4, ln = lane & 15;
  int wy = w >> 1, wx = w & 1;
  __shared__ unsigned short A_l[64][42];
  __shared__ unsigned short B_l[128][40];
  __shared__ float scs[256], shs[256];
  __shared__ float g_m[8], g_r[8];
  if (tid < 8) {
    float S = 0.f, Q = 0.f;
    for (int i = 0; i < 8; ++i) {
      float2 pp = part[b * 64 + tid * 8 + i];
      S += pp.x; Q += pp.y;
    }
    float mean = S * (1.f / 32768.f);
    float var = Q * (1.f / 32768.f) - mean * mean;
    g_m[tid] = mean;
    g_r[tid] = rsqrtf(var + 1e-5f);
  }
  __syncthreads();
  {
    int c = tid;
    float sc = g_r[c >> 5] * gamma[c];
    scs[c] = sc;
    shs[c] = beta[c] - g_m[c >> 5] * sc;
  }
  __syncthreads();
  f32x4 acc[2][4];
  for (int i = 0; i < 2; ++i)
    for (int j = 0; j < 4; ++j) acc[i][j] = (f32x4){0.f, 0.f, 0.f, 0.f};
  int cc = tid >> 3, ps = tid & 7;
  for (int kc = 0; kc < 256; kc += 32) {
    // A stage: 32 c-rows x 64 p, fp32 -> normalize -> bf16 -> transpose
    {
      float sc = scs[kc + cc], sh = shs[kc + cc];
      const float* xr = x + ((size_t)(b * CC + kc + cc)) * PP + p0;
#pragma unroll
      for (int i = 0; i < 2; ++i) {
        int p = ps * 4 + 32 * i;
        float4 v = *(const float4*)(xr + p);
        A_l[p + 0][cc] = f2bf(v.x * sc + sh);
        A_l[p + 1][cc] = f2bf(v.y * sc + sh);
        A_l[p + 2][cc] = f2bf(v.z * sc + sh);
        A_l[p + 3][cc] = f2bf(v.w * sc + sh);
      }
    }
    // B stage: 128 o-rows x 32 c bf16 weights
    for (int it = 0; it < 2; ++it) {
      int l = tid + 256 * it;
      int row = l >> 2, seg = l & 3;
      *(short8*)&B_l[row][seg * 8] =
          *(const short8*)(wbf + (size_t)(o0 + row) * CC + kc + seg * 8);
    }
    __syncthreads();
    short8 af[2], bfr[4];
    for (int i = 0; i < 2; ++i)
      af[i] = *(const short8*)&A_l[wy * 32 + i * 16 + ln][lq * 8];
    for (int j = 0; j < 4; ++j)
      bfr[j] = *(const short8*)&B_l[wx * 64 + j * 16 + ln][lq * 8];
    for (int i = 0; i < 2; ++i)
      for (int j = 0; j < 4; ++j) acc[i][j] = mfma16(af[i], bfr[j], acc[i][j]);
    __syncthreads();
  }
  for (int i = 0; i < 2; ++i) {
    for (int j = 0; j < 4; ++j) {
      int o = o0 + wx * 64 + j * 16 + ln;
      int s = o >> 8, h = (o >> 6) & 3, ch = o & 63;
      float bias = qkvb[o];
      float mul = (s == 0) ? QSCALE : 1.0f;
      size_t bh = (size_t)b * NH + h;
      int pbase = p0 + wy * 32 + i * 16 + lq * 4;
      if (s == 2) {
        union { unsigned short u[4]; u64 ll; } pk;
#pragma unroll
        for (int r = 0; r < 4; ++r) pk.u[r] = f2bf(acc[i][j][r] + bias);
        *(u64*)(vT + (bh * DH + ch) * PP + pbase) = pk.ll;
      } else {
        unsigned short* dst = (s == 0) ? qb : kb;
#pragma unroll
        for (int r = 0; r < 4; ++r)
          dst[(bh * PP + pbase + r) * DH + ch] =
              f2bf((acc[i][j][r] + bias) * mul);
      }
    }
  }
}

// ------------- Kernel 3: flash attention, 32x32 MFMA -----------------------
// Grid linearized 512; decode keeps the 16 d-tiles sharing one (h,b) K/V
// (256 KB) on the SAME XCD -> 16x K/V re-reads served from that L2.
__global__ __launch_bounds__(256, 2) void attn(
    const unsigned short* __restrict__ qb, const unsigned short* __restrict__ kb,
    const unsigned short* __restrict__ vT, unsigned short* __restrict__ attnT) {
  int bid = blockIdx.x;
  int c8 = bid & 7, rr = bid >> 3;   // rr: 0..63
  int t16 = rr & 15, base = rr >> 4; // t16: d-tile, base: 0..3
  int g = base * 8 + c8;             // 0..31 (h,b) group, same XCD
  int h = g & 3, b = g >> 2;
  int d0 = t16 * 64;
  int tid = threadIdx.x;
  int w = tid >> 6, lane = tid & 63;
  int n = lane & 31, hi = lane >> 5;
  int wd = w & 1, we = w >> 1;
  size_t bh = (size_t)b * NH + h;
  const unsigned short* qbase = qb + bh * PP * DH;
  const unsigned short* kbase = kb + bh * PP * DH;
  const unsigned short* vbase = vT + bh * DH * PP;

  __shared__ __align__(16) char smem[32768];
  unsigned short* K_ls = (unsigned short*)smem;            // [128][64] swz
  unsigned short* V_ls = (unsigned short*)(smem + 16384);  // [64][128] swz
  float* Ored = (float*)smem;                              // [128][34]
  float* lsred = (float*)(smem + 17408);                   // [64]
  unsigned short* O_l = (unsigned short*)(smem + 17664);   // [64][72]

#define KIDX(e, cb) ((e) * 64 + (((cb) ^ ((e) & 7)) << 3))
#define VIDX(ch, cb, off) ((ch) * 128 + (((cb) ^ ((ch) & 7)) << 3) + (off))

  int ke = tid >> 1, kseg = tid & 1;   // K: 128 rows x 2 half-rows
  int vch = tid >> 2, vseg = tid & 3;  // V: 64 rows x 4 quarter-rows

  short8 qf[4];
  {
    int dq = d0 + wd * 32 + n;
#pragma unroll
    for (int kc = 0; kc < 4; ++kc)
      qf[kc] = *(const short8*)(qbase + (size_t)dq * DH + kc * 16 + hi * 8);
  }
  float l_sum = 0.f;
  f32x16 o_acc[2];
#pragma unroll
  for (int i = 0; i < 16; ++i) { o_acc[0][i] = 0.f; o_acc[1][i] = 0.f; }

  short8 kr[4], vr[4];
#pragma unroll
  for (int i = 0; i < 4; ++i)
    kr[i] = *(const short8*)(kbase + (size_t)ke * DH + kseg * 32 + i * 8);
#pragma unroll
  for (int i = 0; i < 4; ++i)
    vr[i] = *(const short8*)(vbase + (size_t)vch * PP + vseg * 32 + i * 8);

  for (int e0 = 0; e0 < PP; e0 += 128) {
#pragma unroll
    for (int i = 0; i < 4; ++i)
      *(short8*)&K_ls[KIDX(ke, kseg * 4 + i)] = kr[i];
#pragma unroll
    for (int i = 0; i < 4; ++i) {
      int acb = vseg * 4 + i;     // actual 8-col chunk (0..15)
      int blkA = acb >> 1;        // 16-col block
      int h8 = acb & 1;
      union { short8 v; u64 q[2]; } uv; uv.v = vr[i];
      *(u64*)&V_ls[VIDX(vch, blkA * 2 + 0, h8 * 4)] = uv.q[0];
      *(u64*)&V_ls[VIDX(vch, blkA * 2 + 1, h8 * 4)] = uv.q[1];
    }
    if (e0 + 128 < PP) {
      int en = e0 + 128;
#pragma unroll
      for (int i = 0; i < 4; ++i)
        kr[i] = *(const short8*)(kbase + (size_t)(en + ke) * DH + kseg * 32 + i * 8);
#pragma unroll
      for (int i = 0; i < 4; ++i)
        vr[i] = *(const short8*)(vbase + (size_t)vch * PP + en + vseg * 32 + i * 8);
    }
    __syncthreads();
    u64 pk[2][4];
#pragma unroll
    for (int t = 0; t < 2; ++t) {
      f32x16 s;
#pragma unroll
      for (int i = 0; i < 16; ++i) s[i] = 0.f;
      int erow = we * 64 + t * 32 + n;
#pragma unroll
      for (int kc = 0; kc < 4; ++kc) {
        short8 af = *(const short8*)&K_ls[KIDX(erow, kc * 2 + hi)];
        s = mfma32(af, qf[kc], s);
      }
#pragma unroll
      for (int gg = 0; gg < 4; ++gg) {
        float p0 = __builtin_amdgcn_exp2f(fminf(s[4 * gg + 0], 86.f));
        float p1 = __builtin_amdgcn_exp2f(fminf(s[4 * gg + 1], 86.f));
        float p2 = __builtin_amdgcn_exp2f(fminf(s[4 * gg + 2], 86.f));
        float p3 = __builtin_amdgcn_exp2f(fminf(s[4 * gg + 3], 86.f));
        l_sum += (p0 + p1) + (p2 + p3);
        union { unsigned short u[4]; u64 ll; } pkk;
        pkk.u[0] = f2bf(p0); pkk.u[1] = f2bf(p1);
        pkk.u[2] = f2bf(p2); pkk.u[3] = f2bf(p3);
        pk[t][gg] = pkk.ll;
      }
    }
#pragma unroll
    for (int t = 0; t < 2; ++t) {
#pragma unroll
      for (int c = 0; c < 2; ++c) {
        union { u64 q[2]; short8 v; } pf;
        pf.q[0] = pk[t][2 * c];
        pf.q[1] = pk[t][2 * c + 1];
        int cb = we * 8 + t * 4 + c * 2 + hi;
#pragma unroll
        for (int mt = 0; mt < 2; ++mt) {
          int ch = mt * 32 + n;
          short8 af = *(const short8*)&V_ls[VIDX(ch, cb, 0)];
          o_acc[mt] = mfma32(af, pf.v, o_acc[mt]);
        }
      }
    }
    __syncthreads();
  }
  l_sum += __shfl_xor(l_sum, 32);
  if (we == 1) {
    if (hi == 0) lsred[wd * 32 + n] = l_sum;
#pragma unroll
    for (int mt = 0; mt < 2; ++mt)
#pragma unroll
      for (int r = 0; r < 16; ++r) {
        int chl = (r & 3) + 8 * (r >> 2) + 4 * hi;
        Ored[(wd * 64 + mt * 32 + chl) * 34 + n] = o_acc[mt][r];
      }
  }
  __syncthreads();
  if (we == 0) {
    float inv = 1.f / (l_sum + lsred[wd * 32 + n]);
#pragma unroll
    for (int mt = 0; mt < 2; ++mt) {
#pragma unroll
      for (int gg = 0; gg < 4; ++gg) {
        union { unsigned short u[4]; u64 ll; } pkk;
#pragma unroll
        for (int q = 0; q < 4; ++q) {
          int r = gg * 4 + q;
          int chl = q + 8 * gg + 4 * hi;
          float v = (o_acc[mt][r] + Ored[(wd * 64 + mt * 32 + chl) * 34 + n]) * inv;
          pkk.u[q] = f2bf(v);
        }
        *(u64*)&O_l[(wd * 32 + n) * 72 + mt * 32 + gg * 8 + 4 * hi] = pkk.ll;
      }
    }
  }
  __syncthreads();
  for (int it = 0; it < 2; ++it) {
    int l2 = tid + 256 * it;
    int dd = l2 >> 3, seg = l2 & 7;
    *(short8*)(attnT + ((size_t)b * PP + d0 + dd) * CC + h * DH + seg * 8) =
        *(const short8*)&O_l[dd * 72 + seg * 8];
  }
#undef KIDX
#undef VIDX
}

// ------------- Kernel 4: proj GEMM + bias + residual (fp32 out) ------------
// Tile 64p x 64o -> grid 512 = 2 blocks/CU (was 256 = 1/CU = 1 wave/SIMD;
// a memory-bound kernel at 1 wave/SIMD cannot hide HBM latency).
// 4 o-tiles sharing one (p0,b) attnT slice stay on the same XCD.
__global__ __launch_bounds__(256) void proj_gemm(
    const unsigned short* __restrict__ attnT, const unsigned short* __restrict__ pwbf,
    const float* __restrict__ projb, const float* __restrict__ x,
    float* __restrict__ out) {
  int bid = blockIdx.x;
  int c8 = bid & 7, rr = bid >> 3;   // rr: 0..63
  int t = rr & 3, base = rr >> 2;    // t: o-tile, base: 0..15
  int p0 = base * 64, b = c8, o0 = t * 64;
  int tid = threadIdx.x;
  int w = tid >> 6, lane = tid & 63, lq = lane >> 4, ln = lane & 15;
  __shared__ unsigned short A_l[64][40];
  __shared__ unsigned short B_l[64][40];
  f32x4 acc[4];
  for (int i = 0; i < 4; ++i) acc[i] = (f32x4){0.f, 0.f, 0.f, 0.f};
  for (int kc = 0; kc < 256; kc += 32) {
    {
      int row = tid >> 2, seg = tid & 3;
      *(short8*)&A_l[row][seg * 8] =
          *(const short8*)(pwbf + (size_t)(o0 + row) * CC + kc + seg * 8);
      *(short8*)&B_l[row][seg * 8] =
          *(const short8*)(attnT + ((size_t)b * PP + p0 + row) * CC + kc + seg * 8);
    }
    __syncthreads();
    short8 af[4];
    for (int i = 0; i < 4; ++i)
      af[i] = *(const short8*)&A_l[i * 16 + ln][lq * 8];
    short8 bfr = *(const short8*)&B_l[w * 16 + ln][lq * 8];
    for (int i = 0; i < 4; ++i) acc[i] = mfma16(af[i], bfr, acc[i]);
    __syncthreads();
  }
  int p = p0 + w * 16 + ln;
  for (int i = 0; i < 4; ++i) {
    for (int r = 0; r < 4; ++r) {
      int o = o0 + i * 16 + lq * 4 + r;
      size_t idx = ((size_t)b * CC + o) * PP + p;
      out[idx] = x[idx] + projb[o] + acc[i][r];
    }
  }
}

// ---------------------------------------------------------------------------
extern "C" void kernel_launch(void* const* d_in, const int* in_sizes, int n_in,
                              void* d_out, int out_size, void* d_ws, size_t ws_size,
                              hipStream_t stream) {
  const float* x = (const float*)d_in[0];
  const float* gamma = (const float*)d_in[1];
  const float* beta = (const float*)d_in[2];
  const float* qkvw = (const float*)d_in[3];
  const float* qkvb = (const float*)d_in[4];
  const float* projw = (const float*)d_in[5];
  const float* projb = (const float*)d_in[6];
  float* out = (float*)d_out;
  char* ws = (char*)d_ws;

  float2* part = (float2*)(ws + 0);                        //  4 KB
  unsigned short* wall = (unsigned short*)(ws + 4210688);  // 512 KB
  unsigned short* pwbf = wall + 768 * 256;
  unsigned short* qb = (unsigned short*)(ws + 4734976);      // 4 MB
  unsigned short* kb = (unsigned short*)(ws + 8929280);      // 4 MB
  unsigned short* vT = (unsigned short*)(ws + 13123584);     // 4 MB
  unsigned short* attnT = (unsigned short*)(ws + 17317888);  // 4 MB

  prep<<<768, 256, 0, stream>>>(x, part, qkvw, projw, wall);
  nqkv<<<768, 256, 0, stream>>>(x, part, gamma, beta, wall, qkvb, qb, kb, vT);
  attn<<<512, 256, 0, stream>>>(qb, kb, vT, attnT);
  proj_gemm<<<512, 256, 0, stream>>>(attnT, pwbf, projb, x, out);
}